// Round 7
// baseline (101.127 us; speedup 1.0000x reference)
//
#include <hip/hip_runtime.h>
#include <stdint.h>

#define LATENT 10
#define MAXLEN 80
#define STEPS  10
#define HIDDEN 32
#define BATCH  512
#define NSEG   16
#define SEGL   5       // MAXLEN / NSEG
#define CPB    32      // chains per block (R22: whole-grid co-residency)
#define TPB    256     // threads per block (4 waves)
#define NST    36      // nrmS chain-stride, padded from 32 (R20 bank analysis)

// Session law (measured):
//  - VGPR ~84 natural is the operating point. R11 (cap 40) and R20
//    (launch_bounds min-waves hint -> VGPR 48) spill catastrophically
//    (R20: 150 MB scratch traffic, k_chain 44->95us). NEVER hint min-waves,
//    NEVER cap registers.
//  - Extra kernel launches cost ~+5us each (R17/R19); optimize IN-PLACE.
//  - R15: cooperative launch breaks graph capture. Two-kernel structure.
//  - R21: barrier-free wave-local structure + prologue-before-RNG overlap:
//    small real win (+1.1us). Kernel is stall-dominated at Occupancy ~22%
//    (~7 of 20 allowed waves/CU) — work removal (R17/R19) is null because
//    stalls, not issue, dominate.
// R22: R20's packaging (CPB=32/TPB=256 -> 1280 blocks = exactly 5
// blocks/CU; LDS 29.7KB x5 = 148.5KB < 160; natural VGPR ~84 -> 20
// waves/CU ALL co-resident, one wavefront generation) + R21's barrier-free
// wave-local structure. R20's failure was solely the register-cap spill;
// this round removes the hint and keeps everything else.
//
// LDS layouts (R16-verified, translation-invariant per 8-chain wave group):
//   scP[c][d*8 + j], chain stride 84: owner ds_read_b128 bank-uniform;
//     partial b32 writes 2-way (free). Base 84*8w = 672w ≡ 0 mod 32.
//   uS[c][d], stride 12: per-step u refresh 5x ds_read_b64 conflict-free;
//     base 12*8w ≡ 0 mod 32.
//   nrmS[n][c], stride NST=36: owner nd-read banks (4r + c) — stride 32
//     would be an 8-way same-bank conflict (R20 analysis).
// A chain's 8 lanes live in ONE wave; DS ops execute in program order per
// wave, so intra-wave write->read needs no barrier. No __syncthreads in
// the kernel at all (skk/shS/RNG production is wave-local, redundant x4
// for skk).
#define SCP_STRIDE 84
#define US_STRIDE  12

// ---------------------------------------------------------------------------
// Threefry-2x32, 20 rounds — bit-exact replica of jax threefry2x32_p.
// ---------------------------------------------------------------------------
__device__ __forceinline__ void tf2x32(uint32_t k0, uint32_t k1,
                                       uint32_t x0, uint32_t x1,
                                       uint32_t& o0, uint32_t& o1) {
  uint32_t ks2 = k0 ^ k1 ^ 0x1BD11BDAu;
  uint32_t v0 = x0 + k0;
  uint32_t v1 = x1 + k1;
#define TF_R(rot) { v0 += v1; v1 = (v1 << (rot)) | (v1 >> (32 - (rot))); v1 ^= v0; }
  TF_R(13) TF_R(15) TF_R(26) TF_R(6)
  v0 += k1;  v1 += ks2 + 1u;
  TF_R(17) TF_R(29) TF_R(16) TF_R(24)
  v0 += ks2; v1 += k0 + 2u;
  TF_R(13) TF_R(15) TF_R(26) TF_R(6)
  v0 += k0;  v1 += k1 + 3u;
  TF_R(17) TF_R(29) TF_R(16) TF_R(24)
  v0 += k1;  v1 += ks2 + 4u;
  TF_R(13) TF_R(15) TF_R(26) TF_R(6)
  v0 += ks2; v1 += k0 + 5u;
#undef TF_R
  o0 = v0; o1 = v1;
}

// JAX uniform(-0.99999994, 1) bits -> sqrt(2)*erfinv(u).
// XLA Giles polynomial; w via fast hw log (1-ulp class, threshold has 10x margin).
__device__ __forceinline__ float bits_to_normal(uint32_t bits) {
  const float lo = -0.99999994f;                                 // nextafter(-1, 0)
  float f = __uint_as_float((bits >> 9) | 0x3f800000u) - 1.0f;   // [0,1)
  float u = fmaf(f, 2.0f, lo);                                   // (hi-lo) rounds to 2.0f
  u = fmaxf(u, lo);
  float w = -__logf(fmaf(-u, u, 1.0f));                          // -ln(1-u^2)
  float p;
  if (w < 5.0f) {
    w -= 2.5f;
    p = 2.81022636e-08f;
    p = fmaf(p, w, 3.43273939e-07f);
    p = fmaf(p, w, -3.5233877e-06f);
    p = fmaf(p, w, -4.39150654e-06f);
    p = fmaf(p, w, 0.00021858087f);
    p = fmaf(p, w, -0.00125372503f);
    p = fmaf(p, w, -0.00417768164f);
    p = fmaf(p, w, 0.246640727f);
    p = fmaf(p, w, 1.50140941f);
  } else {
    w = sqrtf(w) - 3.0f;
    p = -0.000200214257f;
    p = fmaf(p, w, 0.000100950558f);
    p = fmaf(p, w, 0.00134934322f);
    p = fmaf(p, w, -0.00367342844f);
    p = fmaf(p, w, 0.00573950773f);
    p = fmaf(p, w, -0.0076224613f);
    p = fmaf(p, w, 0.00943887047f);
    p = fmaf(p, w, 1.00167406f);
    p = fmaf(p, w, 2.83297682f);
  }
  return 1.4142135623730951f * (p * u);
}

// ---------------------------------------------------------------------------
// Kernel 1: segment totals (unchanged, bit-identical values).
// segtot[s][b][j] = sum_{l in [5s,5s+5)} mu[b,l,:] . W1[l*10:l*10+10, j]
// ---------------------------------------------------------------------------
__global__ __launch_bounds__(256) void k_seg(
    const float* __restrict__ zmean, const float* __restrict__ W1,
    float* __restrict__ segtot) {
  int id = blockIdx.x * 256 + threadIdx.x;    // 0..262143
  int s = id >> 14;                           // segment, block-uniform
  int r = id & 16383;
  int b = r >> 5, j = r & 31;
  float pf0 = 0.0f, pf1 = 0.0f;
#pragma unroll
  for (int t = 0; t < SEGL; ++t) {
    int l = s * SEGL + t;
    const float2* mrow = (const float2*)(zmean + (b * MAXLEN + l) * LATENT);
    float2 m0 = mrow[0], m1 = mrow[1], m2 = mrow[2], m3 = mrow[3], m4 = mrow[4];
    const float* wl = W1 + (l * LATENT) * HIDDEN + j;
    pf0 = fmaf(m0.x, wl[0 * HIDDEN], pf0);
    pf1 = fmaf(m0.y, wl[1 * HIDDEN], pf1);
    pf0 = fmaf(m1.x, wl[2 * HIDDEN], pf0);
    pf1 = fmaf(m1.y, wl[3 * HIDDEN], pf1);
    pf0 = fmaf(m2.x, wl[4 * HIDDEN], pf0);
    pf1 = fmaf(m2.y, wl[5 * HIDDEN], pf1);
    pf0 = fmaf(m3.x, wl[6 * HIDDEN], pf0);
    pf1 = fmaf(m3.y, wl[7 * HIDDEN], pf1);
    pf0 = fmaf(m4.x, wl[8 * HIDDEN], pf0);
    pf1 = fmaf(m4.y, wl[9 * HIDDEN], pf1);
  }
  segtot[(s * BATCH + b) * HIDDEN + j] = pf0 + pf1;
}

// ---------------------------------------------------------------------------
// Kernel 2: block = (i, 32 b's), 256 threads (4 waves), 1280 blocks =
// exactly 5 blocks/CU, all co-resident at natural VGPR. NO __syncthreads.
// ---------------------------------------------------------------------------
__global__ __launch_bounds__(TPB) void k_chain(
    const float* __restrict__ zmean, const float* __restrict__ zlv,
    const float* __restrict__ W1, const float* __restrict__ b1v,
    const float* __restrict__ W2, const float* __restrict__ b2v,
    const float* __restrict__ segtot,
    float* __restrict__ outSeq, float* __restrict__ outErr) {
  __shared__ float nrmS[(STEPS + 1) * LATENT * NST]; // 15840 B, [draw][chain] pad-36
  __shared__ uint32_t skkW[4][2 * (STEPS + 1)];       // 352 B, per-wave subkeys
  __shared__ float shS[CPB * LATENT];                 // 1280 B, 0.5*sstd per (c,d)
  __shared__ float scP[CPB * SCP_STRIDE];             // 10752 B, score partials
  __shared__ float uS[CPB * US_STRIDE];               // 1536 B, normalized state

  const int tid = threadIdx.x;
  const int lane = tid & 63;
  const int wid = tid >> 6;                           // wave w: chains 8w..8w+7
  const int i = blockIdx.x >> 4;                      // block-uniform, 0..79
  const int b0 = (blockIdx.x & 15) << 5;              // 32 b's per block

  // ---- per-wave subkeys (lanes 0..10, redundant per wave; no barrier) ----
  if (lane < (STEPS + 1)) {
    uint32_t a, c;
    tf2x32(0u, 1337u, 0u, (uint32_t)(i * (STEPS + 1) + lane), a, c);
    skkW[wid][2 * lane] = a; skkW[wid][2 * lane + 1] = c;
  }

  // ---- shS fill, wave-local (this wave's 8 chains, 80 entries) ----
  {
    int c8 = lane / 10, d_ = lane - c8 * 10;          // flat 0..63
    int cc = (wid << 3) + c8;
    shS[cc * LATENT + d_] =
        0.5f * sqrtf(expf(zlv[((b0 + cc) * MAXLEN + i) * LATENT + d_]));
    if (lane < 16) {                                  // flat 64..79
      int f2 = 64 + lane;
      int c8b = f2 / 10, d2 = f2 - c8b * 10;
      int cc2 = (wid << 3) + c8b;
      shS[cc2 * LATENT + d2] =
          0.5f * sqrtf(expf(zlv[((b0 + cc2) * MAXLEN + i) * LATENT + d2]));
    }
  }

  const int r = tid & 7;                              // lane-in-chain
  const int jb = r * 4;                               // first hidden unit
  const int cloc = tid >> 3;                          // chain-in-block (cloc>>3==wid)
  const int b = b0 + cloc;
  const int base = (b * MAXLEN + i) * LATENT;

  // ---- prologue loads BEFORE RNG: their latency hides under threefry ----
  // pf = b1 + i*wT + segtot prefix + partial rows + mu_i fold  (R16 order)
  const float* rowT = W1 + (MAXLEN * LATENT) * HIDDEN;
  float pf[4], wT[4];
  const float fi = (float)i;
#pragma unroll
  for (int k = 0; k < 4; ++k) {
    wT[k] = rowT[jb + k];
    pf[k] = fmaf(fi, wT[k], b1v[jb + k]);
  }
  const int fs = i / SEGL;                            // full segments (uniform)
  for (int s2 = 0; s2 < fs; ++s2) {
    float4 t0 = *(const float4*)(segtot + ((size_t)s2 * BATCH + b) * HIDDEN + jb);
    pf[0] += t0.x; pf[1] += t0.y; pf[2] += t0.z; pf[3] += t0.w;
  }
  for (int l = fs * SEGL; l < i; ++l) {               // <= 4 partial l's
    const float2* mrow = (const float2*)(zmean + (b * MAXLEN + l) * LATENT);
    const float* wl = W1 + (l * LATENT) * HIDDEN + jb;
#pragma unroll
    for (int p = 0; p < 5; ++p) {
      float2 m = mrow[p];
      float4 wa = *(const float4*)(wl + (2 * p) * HIDDEN);
      float4 wb = *(const float4*)(wl + (2 * p + 1) * HIDDEN);
      pf[0] = fmaf(m.x, wa.x, pf[0]); pf[1] = fmaf(m.x, wa.y, pf[1]);
      pf[2] = fmaf(m.x, wa.z, pf[2]); pf[3] = fmaf(m.x, wa.w, pf[3]);
      pf[0] = fmaf(m.y, wb.x, pf[0]); pf[1] = fmaf(m.y, wb.y, pf[1]);
      pf[2] = fmaf(m.y, wb.z, pf[2]); pf[3] = fmaf(m.y, wb.w, pf[3]);
    }
  }
  {
    // mu_i fold into pf — same p-ascending, m.x*wa then m.y*wb order as R16
    const float2* zm = (const float2*)(zmean + base);
    const float* W1i = W1 + (i * LATENT) * HIDDEN + jb;
#pragma unroll
    for (int p = 0; p < 5; ++p) {
      float2 m = zm[p];
      float4 wa = *(const float4*)(W1i + (2 * p) * HIDDEN);
      float4 wb = *(const float4*)(W1i + (2 * p + 1) * HIDDEN);
      pf[0] = fmaf(m.x, wa.x, pf[0]); pf[1] = fmaf(m.x, wa.y, pf[1]);
      pf[2] = fmaf(m.x, wa.z, pf[2]); pf[3] = fmaf(m.x, wa.w, pf[3]);
      pf[0] = fmaf(m.y, wb.x, pf[0]); pf[1] = fmaf(m.y, wb.y, pf[1]);
      pf[2] = fmaf(m.y, wb.z, pf[2]); pf[3] = fmaf(m.y, wb.w, pf[3]);
    }
  }

  // ---- RNG, wave-local: this wave's 8 chains x 110 draws (880 of 896) ----
  // Same (n,c)->value mapping as R16/R21; only the producer lane changed.
  const float SQRT_DT = 0.31622776601683794f;
  {
    const uint32_t* skw = skkW[wid];
#pragma unroll
    for (int t = 0; t < 14; ++t) {
      int idx = t * 64 + lane;                        // 0..895
      int n_ = idx >> 3;                              // draw index 0..111
      if (n_ < (STEPS + 1) * LATENT) {
        int c_ = (wid << 3) + (idx & 7);              // block-local chain
        int k_ = (n_ * 205) >> 11;
        int d_ = n_ - k_ * 10;
        uint32_t o0_, o1_;
        tf2x32(skw[2 * k_], skw[2 * k_ + 1], 0u,
               (uint32_t)((b0 + c_) * LATENT + d_), o0_, o1_);
        float v_ = bits_to_normal(o0_ ^ o1_);
        nrmS[n_ * NST + c_] = (n_ < LATENT) ? v_ : v_ * SQRT_DT;
      }
    }
  }

  // ---- w1s build (after RNG; W1i re-load is L2-hot; products order-free) ----
  float w1s[LATENT][4];
  {
    const float2* shp = (const float2*)(shS + cloc * LATENT);
    const float* W1i = W1 + (i * LATENT) * HIDDEN + jb;
#pragma unroll
    for (int p = 0; p < 5; ++p) {
      float2 sh = shp[p];
      float s0 = sh.x + sh.x;                         // == sstd exactly
      float s1 = sh.y + sh.y;
      float4 wa = *(const float4*)(W1i + (2 * p) * HIDDEN);
      float4 wb = *(const float4*)(W1i + (2 * p + 1) * HIDDEN);
      w1s[2 * p][0] = s0 * wa.x; w1s[2 * p][1] = s0 * wa.y;
      w1s[2 * p][2] = s0 * wa.z; w1s[2 * p][3] = s0 * wa.w;
      w1s[2 * p + 1][0] = s1 * wb.x; w1s[2 * p + 1][1] = s1 * wb.y;
      w1s[2 * p + 1][2] = s1 * wb.z; w1s[2 * p + 1][3] = s1 * wb.w;
    }
  }

  // owner state: lane r owns dim r; lanes 0,1 also own dims 8,9.
  float sh0 = shS[cloc * LATENT + r];
  float b2o0 = b2v[r];
  float u0o = nrmS[r * NST + cloc];                   // k = 0 draw (same wave)
  float e0 = 0.0f;
  float sh1 = 0.0f, b2o1 = 0.0f, u1o = 0.0f, e1 = 0.0f;
  if (r < 2) {
    sh1 = shS[cloc * LATENT + 8 + r];
    b2o1 = b2v[8 + r];
    u1o = nrmS[(8 + r) * NST + cloc];
  }
  {
    float* uw = uS + cloc * US_STRIDE;                // publish u0
    uw[r] = u0o;
    if (r < 2) uw[8 + r] = u1o;
  }

  const float* W2q = W2 + jb * LATENT;
  float* scw = scP + cloc * SCP_STRIDE + r;                 // partial writes
  const float* scrd0 = scP + cloc * SCP_STRIDE + r * 8;     // owner reads d=r
  const float* scrd1 = scP + cloc * SCP_STRIDE + (8 + r) * 8;
  const float2* urd = (const float2*)(uS + cloc * US_STRIDE);
  const float* ndp = nrmS + LATENT * NST + cloc;            // k=1 draws base

  for (int s = 0; s < STEPS; ++s) {
    // refresh u from uS (5x ds_read_b64) + HOISTED nd reads (latency overlap)
    float2 ua = urd[0], ub = urd[1], uc = urd[2], ud = urd[3], ue = urd[4];
    float ndv0 = ndp[s * (LATENT * NST) + r * NST];   // pre-scaled by sqrt(dt)
    float ndv1 = 0.0f;
    if (r < 2) ndv1 = ndp[s * (LATENT * NST) + (8 + r) * NST];

    const float ts = (float)s * 0.1f;
    float h[4];
#pragma unroll
    for (int k = 0; k < 4; ++k) h[k] = fmaf(ts, wT[k], pf[k]);
#define ACC(d, val) { h[0] = fmaf((val), w1s[d][0], h[0]); h[1] = fmaf((val), w1s[d][1], h[1]); \
                      h[2] = fmaf((val), w1s[d][2], h[2]); h[3] = fmaf((val), w1s[d][3], h[3]); }
    ACC(0, ua.x) ACC(1, ua.y) ACC(2, ub.x) ACC(3, ub.y) ACC(4, uc.x)
    ACC(5, uc.y) ACC(6, ud.x) ACC(7, ud.y) ACC(8, ue.x) ACC(9, ue.y)
#undef ACC

    // partial score over this lane's 4 hidden units (k=0 via mul == fma(..,0))
    float sc[LATENT];
    {
      float hj = fmaxf(h[0], 0.0f);
      const float2* w2r = (const float2*)(W2q);
#pragma unroll
      for (int p = 0; p < 5; ++p) {
        float2 w = w2r[p];
        sc[2 * p] = hj * w.x; sc[2 * p + 1] = hj * w.y;
      }
    }
#pragma unroll
    for (int k = 1; k < 4; ++k) {
      float hj = fmaxf(h[k], 0.0f);
      const float2* w2r = (const float2*)(W2q + k * LATENT);
#pragma unroll
      for (int p = 0; p < 5; ++p) {
        float2 w = w2r[p];
        sc[2 * p] = fmaf(hj, w.x, sc[2 * p]);
        sc[2 * p + 1] = fmaf(hj, w.y, sc[2 * p + 1]);
      }
    }

    // transpose partials into scP: scP[c][d*8 + r]  (2-way banks: free)
#pragma unroll
    for (int d = 0; d < LATENT; ++d) scw[d * 8] = sc[d];

    // owner: sum the chain's 8 partials with the SAME tree shape as the old
    // xor-butterfly -> bit-identical st; then update only owned dims.
    {
      float4 lo = *(const float4*)(scrd0);
      float4 hi = *(const float4*)(scrd0 + 4);
      float ssum = ((lo.x + lo.y) + (lo.z + lo.w)) +
                   ((hi.x + hi.y) + (hi.z + hi.w));
      float st = ssum + b2o0;
      e0 += fabsf(u0o + st);                          // |logdx - st|, logdx = -u
      u0o = u0o + fmaf(sh0, st, ndv0);
    }
    if (r < 2) {
      float4 lo = *(const float4*)(scrd1);
      float4 hi = *(const float4*)(scrd1 + 4);
      float ssum = ((lo.x + lo.y) + (lo.z + lo.w)) +
                   ((hi.x + hi.y) + (hi.z + hi.w));
      float st = ssum + b2o1;
      e1 += fabsf(u1o + st);
      u1o = u1o + fmaf(sh1, st, ndv1);
    }

    // publish updated u for next step (intra-wave; in-order DS)
    {
      float* uw = uS + cloc * US_STRIDE;
      uw[r] = u0o;
      if (r < 2) uw[8 + r] = u1o;
    }
  }

  // ---- epilogue: owner stores its dims; mu reloaded (identical bits) ----
  {
    float sd0 = sh0 + sh0;                            // == sstd exactly
    outSeq[base + r] = fmaf(sd0, u0o, zmean[base + r]);
    outErr[base + r] = e0;
    if (r < 2) {
      float sd1 = sh1 + sh1;
      outSeq[base + 8 + r] = fmaf(sd1, u1o, zmean[base + 8 + r]);
      outErr[base + 8 + r] = e1;
    }
  }
}

// ---------------------------------------------------------------------------
// Fallback (ws too small): known-correct mono kernel.
// ---------------------------------------------------------------------------
__global__ __launch_bounds__(64) void k_mono(
    const float* __restrict__ zmean, const float* __restrict__ zlv,
    const float* __restrict__ W1, const float* __restrict__ b1v,
    const float* __restrict__ W2, const float* __restrict__ b2v,
    float* __restrict__ outSeq, float* __restrict__ outErr) {
  int i = blockIdx.x >> 3;
  int b = ((blockIdx.x & 7) << 6) + threadIdx.x;
  float pref[HIDDEN];
#pragma unroll
  for (int j = 0; j < HIDDEN; ++j) pref[j] = 0.0f;
  for (int l = 0; l < i; ++l) {
    const float* mrow = zmean + (b * MAXLEN + l) * LATENT;
    const float* wrow = W1 + (l * LATENT) * HIDDEN;
#pragma unroll
    for (int d = 0; d < LATENT; ++d) {
      float m = mrow[d];
#pragma unroll
      for (int j = 0; j < HIDDEN; ++j) pref[j] = fmaf(m, wrow[d * HIDDEN + j], pref[j]);
    }
  }
  const int base = (b * MAXLEN + i) * LATENT;
  float mu[LATENT], sstd[LATENT], xt[LATENT], errs[LATENT];
#pragma unroll
  for (int d = 0; d < LATENT; ++d) {
    mu[d] = zmean[base + d];
    sstd[d] = sqrtf(expf(zlv[base + d]));
  }
  float n0[LATENT];
  {
    uint32_t a, c;
    tf2x32(0u, 1337u, 0u, (uint32_t)(i * (STEPS + 1)), a, c);
#pragma unroll
    for (int d = 0; d < LATENT; ++d) {
      uint32_t o0, o1;
      tf2x32(a, c, 0u, (uint32_t)(b * LATENT + d), o0, o1);
      n0[d] = bits_to_normal(o0 ^ o1);
    }
  }
#pragma unroll
  for (int d = 0; d < LATENT; ++d) { xt[d] = mu[d] + sstd[d] * n0[d]; errs[d] = 0.0f; }
  const float* rowT  = W1 + (MAXLEN * LATENT) * HIDDEN;
  const float* rowsI = W1 + (i * LATENT) * HIDDEN;
  const float SQRT_DT = 0.31622776601683794f;
  for (int s = 0; s < STEPS; ++s) {
    float t = (float)i + (float)s * 0.1f;
    float h[HIDDEN];
#pragma unroll
    for (int j = 0; j < HIDDEN; ++j) h[j] = pref[j];
#pragma unroll
    for (int d = 0; d < LATENT; ++d) {
      float xd = xt[d];
      const float* row = rowsI + d * HIDDEN;
#pragma unroll
      for (int j = 0; j < HIDDEN; ++j) h[j] = fmaf(xd, row[j], h[j]);
    }
    float sc[LATENT];
#pragma unroll
    for (int d = 0; d < LATENT; ++d) sc[d] = b2v[d];
#pragma unroll
    for (int j = 0; j < HIDDEN; ++j) {
      float hj = fmaf(t, rowT[j], h[j]) + b1v[j];
      hj = fmaxf(hj, 0.0f);
      const float* w2r = W2 + j * LATENT;
#pragma unroll
      for (int d = 0; d < LATENT; ++d) sc[d] = fmaf(hj, w2r[d], sc[d]);
    }
    float nd[LATENT];
    {
      uint32_t a, c;
      tf2x32(0u, 1337u, 0u, (uint32_t)(i * (STEPS + 1) + s + 1), a, c);
#pragma unroll
      for (int d = 0; d < LATENT; ++d) {
        uint32_t o0, o1;
        tf2x32(a, c, 0u, (uint32_t)(b * LATENT + d), o0, o1);
        nd[d] = bits_to_normal(o0 ^ o1);
      }
    }
#pragma unroll
    for (int d = 0; d < LATENT; ++d) {
      float logdx = -(xt[d] - mu[d]) / sstd[d];
      errs[d] += fabsf(logdx - sc[d]);
      float dW = nd[d] * SQRT_DT;
      xt[d] = xt[d] + (0.5f * (sstd[d] * sstd[d])) * sc[d] + sstd[d] * dW;
    }
  }
#pragma unroll
  for (int d = 0; d < LATENT; ++d) {
    outSeq[base + d] = xt[d];
    outErr[base + d] = errs[d];
  }
}

// ---------------------------------------------------------------------------
extern "C" void kernel_launch(void* const* d_in, const int* in_sizes, int n_in,
                              void* d_out, int out_size, void* d_ws, size_t ws_size,
                              hipStream_t stream) {
  (void)in_sizes; (void)n_in; (void)out_size;
  const float* zmean = (const float*)d_in[0];
  const float* zlv   = (const float*)d_in[1];
  const float* W1    = (const float*)d_in[2];
  const float* b1v   = (const float*)d_in[3];
  const float* W2    = (const float*)d_in[4];
  const float* b2v   = (const float*)d_in[5];
  float* outSeq = (float*)d_out;
  float* outErr = outSeq + (size_t)BATCH * MAXLEN * LATENT;

  const size_t segBytes = (size_t)NSEG * BATCH * HIDDEN * sizeof(float);   // 1,048,576

  if (ws_size >= segBytes) {
    float* segtot = (float*)d_ws;
    hipLaunchKernelGGL(k_seg, dim3(NSEG * BATCH * HIDDEN / 256), dim3(256), 0, stream,
                       zmean, W1, segtot);
    hipLaunchKernelGGL(k_chain, dim3(MAXLEN * (BATCH / CPB)), dim3(TPB), 0, stream,
                       zmean, zlv, W1, b1v, W2, b2v, segtot, outSeq, outErr);
  } else {
    hipLaunchKernelGGL(k_mono, dim3(MAXLEN * 8), dim3(64), 0, stream,
                       zmean, zlv, W1, b1v, W2, b2v, outSeq, outErr);
  }
}

// Round 10
// 98.879 us; speedup vs baseline: 1.0227x; 1.0227x over previous
//
#include <hip/hip_runtime.h>
#include <stdint.h>

#define LATENT 10
#define MAXLEN 80
#define STEPS  10
#define HIDDEN 32
#define BATCH  512
#define NSEG   16
#define SEGL   5       // MAXLEN / NSEG
#define CPB    16      // chains per block
#define TPB    128     // threads per block (2 waves)

// Session law (measured, R0-R24):
//  - VGPR ~84 natural is the operating point. R11 (cap 40) and R20
//    (launch_bounds min-waves hint -> VGPR 48) spill catastrophically
//    (R20: 150 MB scratch/dispatch, k_chain 44->95us). NEVER hint
//    min-waves, NEVER cap registers.
//  - Extra kernel launches cost ~+5us each (R17/R19); optimize IN-PLACE.
//  - R15: cooperative launch breaks graph capture. Two-kernel structure.
//  - R22 (CPB=32 packaging): null — waves/SIMD is fixed by the 8-lane
//    decomposition (5120 waves = 5/SIMD), packaging can't change it.
//  - R23/R24 (16 lanes/chain): FAILED absmax 8.06 BIT-IDENTICALLY across
//    an LDS-alignment fix — deterministic logic defect, not located by
//    two full audits (index maps, wave-locality, alias sets all check on
//    paper). Direction abandoned without device-side diagnostics.
//  - This file = R21 verbatim (best passing, 99.7us): R16 owner-split
//    step loop + barrier-free wave-local producers + prologue-before-RNG.
//
// R16 LDS layouts:
//   scP[c][d*8 + j], chain stride 84: owner ds_read_b128 bank-uniform;
//     partial b32 writes 2-way (free).
//   uS[c][d], stride 12: per-step u refresh 5x ds_read_b64 conflict-free.
//   nrmS[n][c], stride 16.
// A chain's 8 lanes live in ONE wave; DS ops execute in program order per
// wave, so intra-wave write->read needs no barrier (validated R16/R21).
#define SCP_STRIDE 84
#define US_STRIDE  12

// ---------------------------------------------------------------------------
// Threefry-2x32, 20 rounds — bit-exact replica of jax threefry2x32_p.
// ---------------------------------------------------------------------------
__device__ __forceinline__ void tf2x32(uint32_t k0, uint32_t k1,
                                       uint32_t x0, uint32_t x1,
                                       uint32_t& o0, uint32_t& o1) {
  uint32_t ks2 = k0 ^ k1 ^ 0x1BD11BDAu;
  uint32_t v0 = x0 + k0;
  uint32_t v1 = x1 + k1;
#define TF_R(rot) { v0 += v1; v1 = (v1 << (rot)) | (v1 >> (32 - (rot))); v1 ^= v0; }
  TF_R(13) TF_R(15) TF_R(26) TF_R(6)
  v0 += k1;  v1 += ks2 + 1u;
  TF_R(17) TF_R(29) TF_R(16) TF_R(24)
  v0 += ks2; v1 += k0 + 2u;
  TF_R(13) TF_R(15) TF_R(26) TF_R(6)
  v0 += k0;  v1 += k1 + 3u;
  TF_R(17) TF_R(29) TF_R(16) TF_R(24)
  v0 += k1;  v1 += ks2 + 4u;
  TF_R(13) TF_R(15) TF_R(26) TF_R(6)
  v0 += ks2; v1 += k0 + 5u;
#undef TF_R
  o0 = v0; o1 = v1;
}

// JAX uniform(-0.99999994, 1) bits -> sqrt(2)*erfinv(u).
// XLA Giles polynomial; w via fast hw log (1-ulp class, threshold has 10x margin).
__device__ __forceinline__ float bits_to_normal(uint32_t bits) {
  const float lo = -0.99999994f;                                 // nextafter(-1, 0)
  float f = __uint_as_float((bits >> 9) | 0x3f800000u) - 1.0f;   // [0,1)
  float u = fmaf(f, 2.0f, lo);                                   // (hi-lo) rounds to 2.0f
  u = fmaxf(u, lo);
  float w = -__logf(fmaf(-u, u, 1.0f));                          // -ln(1-u^2)
  float p;
  if (w < 5.0f) {
    w -= 2.5f;
    p = 2.81022636e-08f;
    p = fmaf(p, w, 3.43273939e-07f);
    p = fmaf(p, w, -3.5233877e-06f);
    p = fmaf(p, w, -4.39150654e-06f);
    p = fmaf(p, w, 0.00021858087f);
    p = fmaf(p, w, -0.00125372503f);
    p = fmaf(p, w, -0.00417768164f);
    p = fmaf(p, w, 0.246640727f);
    p = fmaf(p, w, 1.50140941f);
  } else {
    w = sqrtf(w) - 3.0f;
    p = -0.000200214257f;
    p = fmaf(p, w, 0.000100950558f);
    p = fmaf(p, w, 0.00134934322f);
    p = fmaf(p, w, -0.00367342844f);
    p = fmaf(p, w, 0.00573950773f);
    p = fmaf(p, w, -0.0076224613f);
    p = fmaf(p, w, 0.00943887047f);
    p = fmaf(p, w, 1.00167406f);
    p = fmaf(p, w, 2.83297682f);
  }
  return 1.4142135623730951f * (p * u);
}

// ---------------------------------------------------------------------------
// Kernel 1: segment totals (unchanged, bit-identical values).
// segtot[s][b][j] = sum_{l in [5s,5s+5)} mu[b,l,:] . W1[l*10:l*10+10, j]
// ---------------------------------------------------------------------------
__global__ __launch_bounds__(256) void k_seg(
    const float* __restrict__ zmean, const float* __restrict__ W1,
    float* __restrict__ segtot) {
  int id = blockIdx.x * 256 + threadIdx.x;    // 0..262143
  int s = id >> 14;                           // segment, block-uniform
  int r = id & 16383;
  int b = r >> 5, j = r & 31;
  float pf0 = 0.0f, pf1 = 0.0f;
#pragma unroll
  for (int t = 0; t < SEGL; ++t) {
    int l = s * SEGL + t;
    const float2* mrow = (const float2*)(zmean + (b * MAXLEN + l) * LATENT);
    float2 m0 = mrow[0], m1 = mrow[1], m2 = mrow[2], m3 = mrow[3], m4 = mrow[4];
    const float* wl = W1 + (l * LATENT) * HIDDEN + j;
    pf0 = fmaf(m0.x, wl[0 * HIDDEN], pf0);
    pf1 = fmaf(m0.y, wl[1 * HIDDEN], pf1);
    pf0 = fmaf(m1.x, wl[2 * HIDDEN], pf0);
    pf1 = fmaf(m1.y, wl[3 * HIDDEN], pf1);
    pf0 = fmaf(m2.x, wl[4 * HIDDEN], pf0);
    pf1 = fmaf(m2.y, wl[5 * HIDDEN], pf1);
    pf0 = fmaf(m3.x, wl[6 * HIDDEN], pf0);
    pf1 = fmaf(m3.y, wl[7 * HIDDEN], pf1);
    pf0 = fmaf(m4.x, wl[8 * HIDDEN], pf0);
    pf1 = fmaf(m4.y, wl[9 * HIDDEN], pf1);
  }
  segtot[(s * BATCH + b) * HIDDEN + j] = pf0 + pf1;
}

// ---------------------------------------------------------------------------
// Kernel 2: block = (i, 16 b's), 128 threads (2 waves), 2560 blocks.
// NO __syncthreads anywhere: all LDS comms intra-wave.
// ---------------------------------------------------------------------------
__global__ __launch_bounds__(TPB) void k_chain(
    const float* __restrict__ zmean, const float* __restrict__ zlv,
    const float* __restrict__ W1, const float* __restrict__ b1v,
    const float* __restrict__ W2, const float* __restrict__ b2v,
    const float* __restrict__ segtot,
    float* __restrict__ outSeq, float* __restrict__ outErr) {
  __shared__ float nrmS[(STEPS + 1) * LATENT * CPB];  // 7040 B, [draw][chain]
  __shared__ uint32_t skkW[2][2 * (STEPS + 1)];       // 176 B, per-wave subkeys
  __shared__ float shS[CPB * LATENT];                 // 640 B, 0.5*sstd per (c,d)
  __shared__ float scP[CPB * SCP_STRIDE];             // 5376 B, score partials
  __shared__ float uS[CPB * US_STRIDE];               // 768 B, normalized state

  const int tid = threadIdx.x;
  const int lane = tid & 63;
  const int wid = tid >> 6;                           // wave 0: chains 0-7, wave 1: 8-15
  const int i = blockIdx.x >> 5;                      // block-uniform
  const int b0 = (blockIdx.x & 31) << 4;

  // ---- per-wave subkeys (lanes 0..10, redundant per wave; no barrier) ----
  if (lane < (STEPS + 1)) {
    uint32_t a, c;
    tf2x32(0u, 1337u, 0u, (uint32_t)(i * (STEPS + 1) + lane), a, c);
    skkW[wid][2 * lane] = a; skkW[wid][2 * lane + 1] = c;
  }

  // ---- shS fill, wave-local (entries of this wave's 8 chains only) ----
  {
    int c8 = lane / 10, d_ = lane - c8 * 10;          // flat 0..63
    int cc = (wid << 3) + c8;
    shS[cc * LATENT + d_] =
        0.5f * sqrtf(expf(zlv[((b0 + cc) * MAXLEN + i) * LATENT + d_]));
    if (lane < 16) {                                  // flat 64..79
      int f2 = 64 + lane;
      int c8b = f2 / 10, d2 = f2 - c8b * 10;
      int cc2 = (wid << 3) + c8b;
      shS[cc2 * LATENT + d2] =
          0.5f * sqrtf(expf(zlv[((b0 + cc2) * MAXLEN + i) * LATENT + d2]));
    }
  }

  const int r = tid & 7;                              // lane-in-chain
  const int jb = r * 4;                               // first hidden unit
  const int cloc = tid >> 3;                          // chain-in-block (cloc>>3==wid)
  const int b = b0 + cloc;
  const int base = (b * MAXLEN + i) * LATENT;

  // ---- prologue loads BEFORE RNG: their latency hides under threefry ----
  // pf = b1 + i*wT + segtot prefix + partial rows + mu_i fold  (R16 order)
  const float* rowT = W1 + (MAXLEN * LATENT) * HIDDEN;
  float pf[4], wT[4];
  const float fi = (float)i;
#pragma unroll
  for (int k = 0; k < 4; ++k) {
    wT[k] = rowT[jb + k];
    pf[k] = fmaf(fi, wT[k], b1v[jb + k]);
  }
  const int fs = i / SEGL;                            // full segments (uniform)
  for (int s2 = 0; s2 < fs; ++s2) {
    float4 t0 = *(const float4*)(segtot + ((size_t)s2 * BATCH + b) * HIDDEN + jb);
    pf[0] += t0.x; pf[1] += t0.y; pf[2] += t0.z; pf[3] += t0.w;
  }
  for (int l = fs * SEGL; l < i; ++l) {               // <= 4 partial l's
    const float2* mrow = (const float2*)(zmean + (b * MAXLEN + l) * LATENT);
    const float* wl = W1 + (l * LATENT) * HIDDEN + jb;
#pragma unroll
    for (int p = 0; p < 5; ++p) {
      float2 m = mrow[p];
      float4 wa = *(const float4*)(wl + (2 * p) * HIDDEN);
      float4 wb = *(const float4*)(wl + (2 * p + 1) * HIDDEN);
      pf[0] = fmaf(m.x, wa.x, pf[0]); pf[1] = fmaf(m.x, wa.y, pf[1]);
      pf[2] = fmaf(m.x, wa.z, pf[2]); pf[3] = fmaf(m.x, wa.w, pf[3]);
      pf[0] = fmaf(m.y, wb.x, pf[0]); pf[1] = fmaf(m.y, wb.y, pf[1]);
      pf[2] = fmaf(m.y, wb.z, pf[2]); pf[3] = fmaf(m.y, wb.w, pf[3]);
    }
  }
  {
    // mu_i fold into pf — same p-ascending, m.x*wa then m.y*wb order as R16
    const float2* zm = (const float2*)(zmean + base);
    const float* W1i = W1 + (i * LATENT) * HIDDEN + jb;
#pragma unroll
    for (int p = 0; p < 5; ++p) {
      float2 m = zm[p];
      float4 wa = *(const float4*)(W1i + (2 * p) * HIDDEN);
      float4 wb = *(const float4*)(W1i + (2 * p + 1) * HIDDEN);
      pf[0] = fmaf(m.x, wa.x, pf[0]); pf[1] = fmaf(m.x, wa.y, pf[1]);
      pf[2] = fmaf(m.x, wa.z, pf[2]); pf[3] = fmaf(m.x, wa.w, pf[3]);
      pf[0] = fmaf(m.y, wb.x, pf[0]); pf[1] = fmaf(m.y, wb.y, pf[1]);
      pf[2] = fmaf(m.y, wb.z, pf[2]); pf[3] = fmaf(m.y, wb.w, pf[3]);
    }
  }

  // ---- RNG, wave-local: this wave's 8 chains x 110 draws (880 of 896) ----
  // Same (n,c)->value mapping as R16; only the producer lane changed.
  const float SQRT_DT = 0.31622776601683794f;
  {
    const uint32_t* skw = skkW[wid];
#pragma unroll
    for (int t = 0; t < 14; ++t) {
      int idx = t * 64 + lane;                        // 0..895
      int n_ = idx >> 3;                              // draw index 0..111
      if (n_ < (STEPS + 1) * LATENT) {
        int c_ = (wid << 3) + (idx & 7);              // block-local chain
        int k_ = (n_ * 205) >> 11;
        int d_ = n_ - k_ * 10;
        uint32_t o0_, o1_;
        tf2x32(skw[2 * k_], skw[2 * k_ + 1], 0u,
               (uint32_t)((b0 + c_) * LATENT + d_), o0_, o1_);
        float v_ = bits_to_normal(o0_ ^ o1_);
        nrmS[n_ * CPB + c_] = (n_ < LATENT) ? v_ : v_ * SQRT_DT;
      }
    }
  }

  // ---- w1s build (after RNG; W1i re-load is L2-hot; products order-free) ----
  float w1s[LATENT][4];
  {
    const float2* shp = (const float2*)(shS + cloc * LATENT);
    const float* W1i = W1 + (i * LATENT) * HIDDEN + jb;
#pragma unroll
    for (int p = 0; p < 5; ++p) {
      float2 sh = shp[p];
      float s0 = sh.x + sh.x;                         // == sstd exactly
      float s1 = sh.y + sh.y;
      float4 wa = *(const float4*)(W1i + (2 * p) * HIDDEN);
      float4 wb = *(const float4*)(W1i + (2 * p + 1) * HIDDEN);
      w1s[2 * p][0] = s0 * wa.x; w1s[2 * p][1] = s0 * wa.y;
      w1s[2 * p][2] = s0 * wa.z; w1s[2 * p][3] = s0 * wa.w;
      w1s[2 * p + 1][0] = s1 * wb.x; w1s[2 * p + 1][1] = s1 * wb.y;
      w1s[2 * p + 1][2] = s1 * wb.z; w1s[2 * p + 1][3] = s1 * wb.w;
    }
  }

  // owner state: lane r owns dim r; lanes 0,1 also own dims 8,9.
  float sh0 = shS[cloc * LATENT + r];
  float b2o0 = b2v[r];
  float u0o = nrmS[r * CPB + cloc];                   // k = 0 draw (same wave)
  float e0 = 0.0f;
  float sh1 = 0.0f, b2o1 = 0.0f, u1o = 0.0f, e1 = 0.0f;
  if (r < 2) {
    sh1 = shS[cloc * LATENT + 8 + r];
    b2o1 = b2v[8 + r];
    u1o = nrmS[(8 + r) * CPB + cloc];
  }
  {
    float* uw = uS + cloc * US_STRIDE;                // publish u0
    uw[r] = u0o;
    if (r < 2) uw[8 + r] = u1o;
  }

  const float* W2q = W2 + jb * LATENT;
  float* scw = scP + cloc * SCP_STRIDE + r;                 // partial writes
  const float* scrd0 = scP + cloc * SCP_STRIDE + r * 8;     // owner reads d=r
  const float* scrd1 = scP + cloc * SCP_STRIDE + (8 + r) * 8;
  const float2* urd = (const float2*)(uS + cloc * US_STRIDE);
  const float* ndp = nrmS + LATENT * CPB + cloc;            // k=1 draws base

  for (int s = 0; s < STEPS; ++s) {
    // refresh u from uS (5x ds_read_b64) + HOISTED nd reads (latency overlap)
    float2 ua = urd[0], ub = urd[1], uc = urd[2], ud = urd[3], ue = urd[4];
    float ndv0 = ndp[s * (LATENT * CPB) + r * CPB];   // pre-scaled by sqrt(dt)
    float ndv1 = 0.0f;
    if (r < 2) ndv1 = ndp[s * (LATENT * CPB) + (8 + r) * CPB];

    const float ts = (float)s * 0.1f;
    float h[4];
#pragma unroll
    for (int k = 0; k < 4; ++k) h[k] = fmaf(ts, wT[k], pf[k]);
#define ACC(d, val) { h[0] = fmaf((val), w1s[d][0], h[0]); h[1] = fmaf((val), w1s[d][1], h[1]); \
                      h[2] = fmaf((val), w1s[d][2], h[2]); h[3] = fmaf((val), w1s[d][3], h[3]); }
    ACC(0, ua.x) ACC(1, ua.y) ACC(2, ub.x) ACC(3, ub.y) ACC(4, uc.x)
    ACC(5, uc.y) ACC(6, ud.x) ACC(7, ud.y) ACC(8, ue.x) ACC(9, ue.y)
#undef ACC

    // partial score over this lane's 4 hidden units (k=0 via mul == fma(..,0))
    float sc[LATENT];
    {
      float hj = fmaxf(h[0], 0.0f);
      const float2* w2r = (const float2*)(W2q);
#pragma unroll
      for (int p = 0; p < 5; ++p) {
        float2 w = w2r[p];
        sc[2 * p] = hj * w.x; sc[2 * p + 1] = hj * w.y;
      }
    }
#pragma unroll
    for (int k = 1; k < 4; ++k) {
      float hj = fmaxf(h[k], 0.0f);
      const float2* w2r = (const float2*)(W2q + k * LATENT);
#pragma unroll
      for (int p = 0; p < 5; ++p) {
        float2 w = w2r[p];
        sc[2 * p] = fmaf(hj, w.x, sc[2 * p]);
        sc[2 * p + 1] = fmaf(hj, w.y, sc[2 * p + 1]);
      }
    }

    // transpose partials into scP: scP[c][d*8 + r]  (2-way banks: free)
#pragma unroll
    for (int d = 0; d < LATENT; ++d) scw[d * 8] = sc[d];

    // owner: sum the chain's 8 partials with the SAME tree shape as the old
    // xor-butterfly -> bit-identical st; then update only owned dims.
    {
      float4 lo = *(const float4*)(scrd0);
      float4 hi = *(const float4*)(scrd0 + 4);
      float ssum = ((lo.x + lo.y) + (lo.z + lo.w)) +
                   ((hi.x + hi.y) + (hi.z + hi.w));
      float st = ssum + b2o0;
      e0 += fabsf(u0o + st);                          // |logdx - st|, logdx = -u
      u0o = u0o + fmaf(sh0, st, ndv0);
    }
    if (r < 2) {
      float4 lo = *(const float4*)(scrd1);
      float4 hi = *(const float4*)(scrd1 + 4);
      float ssum = ((lo.x + lo.y) + (lo.z + lo.w)) +
                   ((hi.x + hi.y) + (hi.z + hi.w));
      float st = ssum + b2o1;
      e1 += fabsf(u1o + st);
      u1o = u1o + fmaf(sh1, st, ndv1);
    }

    // publish updated u for next step (intra-wave; in-order DS)
    {
      float* uw = uS + cloc * US_STRIDE;
      uw[r] = u0o;
      if (r < 2) uw[8 + r] = u1o;
    }
  }

  // ---- epilogue: owner stores its dims; mu reloaded (identical bits) ----
  {
    float sd0 = sh0 + sh0;                            // == sstd exactly
    outSeq[base + r] = fmaf(sd0, u0o, zmean[base + r]);
    outErr[base + r] = e0;
    if (r < 2) {
      float sd1 = sh1 + sh1;
      outSeq[base + 8 + r] = fmaf(sd1, u1o, zmean[base + 8 + r]);
      outErr[base + 8 + r] = e1;
    }
  }
}

// ---------------------------------------------------------------------------
// Fallback (ws too small): known-correct mono kernel.
// ---------------------------------------------------------------------------
__global__ __launch_bounds__(64) void k_mono(
    const float* __restrict__ zmean, const float* __restrict__ zlv,
    const float* __restrict__ W1, const float* __restrict__ b1v,
    const float* __restrict__ W2, const float* __restrict__ b2v,
    float* __restrict__ outSeq, float* __restrict__ outErr) {
  int i = blockIdx.x >> 3;
  int b = ((blockIdx.x & 7) << 6) + threadIdx.x;
  float pref[HIDDEN];
#pragma unroll
  for (int j = 0; j < HIDDEN; ++j) pref[j] = 0.0f;
  for (int l = 0; l < i; ++l) {
    const float* mrow = zmean + (b * MAXLEN + l) * LATENT;
    const float* wrow = W1 + (l * LATENT) * HIDDEN;
#pragma unroll
    for (int d = 0; d < LATENT; ++d) {
      float m = mrow[d];
#pragma unroll
      for (int j = 0; j < HIDDEN; ++j) pref[j] = fmaf(m, wrow[d * HIDDEN + j], pref[j]);
    }
  }
  const int base = (b * MAXLEN + i) * LATENT;
  float mu[LATENT], sstd[LATENT], xt[LATENT], errs[LATENT];
#pragma unroll
  for (int d = 0; d < LATENT; ++d) {
    mu[d] = zmean[base + d];
    sstd[d] = sqrtf(expf(zlv[base + d]));
  }
  float n0[LATENT];
  {
    uint32_t a, c;
    tf2x32(0u, 1337u, 0u, (uint32_t)(i * (STEPS + 1)), a, c);
#pragma unroll
    for (int d = 0; d < LATENT; ++d) {
      uint32_t o0, o1;
      tf2x32(a, c, 0u, (uint32_t)(b * LATENT + d), o0, o1);
      n0[d] = bits_to_normal(o0 ^ o1);
    }
  }
#pragma unroll
  for (int d = 0; d < LATENT; ++d) { xt[d] = mu[d] + sstd[d] * n0[d]; errs[d] = 0.0f; }
  const float* rowT  = W1 + (MAXLEN * LATENT) * HIDDEN;
  const float* rowsI = W1 + (i * LATENT) * HIDDEN;
  const float SQRT_DT = 0.31622776601683794f;
  for (int s = 0; s < STEPS; ++s) {
    float t = (float)i + (float)s * 0.1f;
    float h[HIDDEN];
#pragma unroll
    for (int j = 0; j < HIDDEN; ++j) h[j] = pref[j];
#pragma unroll
    for (int d = 0; d < LATENT; ++d) {
      float xd = xt[d];
      const float* row = rowsI + d * HIDDEN;
#pragma unroll
      for (int j = 0; j < HIDDEN; ++j) h[j] = fmaf(xd, row[j], h[j]);
    }
    float sc[LATENT];
#pragma unroll
    for (int d = 0; d < LATENT; ++d) sc[d] = b2v[d];
#pragma unroll
    for (int j = 0; j < HIDDEN; ++j) {
      float hj = fmaf(t, rowT[j], h[j]) + b1v[j];
      hj = fmaxf(hj, 0.0f);
      const float* w2r = W2 + j * LATENT;
#pragma unroll
      for (int d = 0; d < LATENT; ++d) sc[d] = fmaf(hj, w2r[d], sc[d]);
    }
    float nd[LATENT];
    {
      uint32_t a, c;
      tf2x32(0u, 1337u, 0u, (uint32_t)(i * (STEPS + 1) + s + 1), a, c);
#pragma unroll
      for (int d = 0; d < LATENT; ++d) {
        uint32_t o0, o1;
        tf2x32(a, c, 0u, (uint32_t)(b * LATENT + d), o0, o1);
        nd[d] = bits_to_normal(o0 ^ o1);
      }
    }
#pragma unroll
    for (int d = 0; d < LATENT; ++d) {
      float logdx = -(xt[d] - mu[d]) / sstd[d];
      errs[d] += fabsf(logdx - sc[d]);
      float dW = nd[d] * SQRT_DT;
      xt[d] = xt[d] + (0.5f * (sstd[d] * sstd[d])) * sc[d] + sstd[d] * dW;
    }
  }
#pragma unroll
  for (int d = 0; d < LATENT; ++d) {
    outSeq[base + d] = xt[d];
    outErr[base + d] = errs[d];
  }
}

// ---------------------------------------------------------------------------
extern "C" void kernel_launch(void* const* d_in, const int* in_sizes, int n_in,
                              void* d_out, int out_size, void* d_ws, size_t ws_size,
                              hipStream_t stream) {
  (void)in_sizes; (void)n_in; (void)out_size;
  const float* zmean = (const float*)d_in[0];
  const float* zlv   = (const float*)d_in[1];
  const float* W1    = (const float*)d_in[2];
  const float* b1v   = (const float*)d_in[3];
  const float* W2    = (const float*)d_in[4];
  const float* b2v   = (const float*)d_in[5];
  float* outSeq = (float*)d_out;
  float* outErr = outSeq + (size_t)BATCH * MAXLEN * LATENT;

  const size_t segBytes = (size_t)NSEG * BATCH * HIDDEN * sizeof(float);   // 1,048,576

  if (ws_size >= segBytes) {
    float* segtot = (float*)d_ws;
    hipLaunchKernelGGL(k_seg, dim3(NSEG * BATCH * HIDDEN / 256), dim3(256), 0, stream,
                       zmean, W1, segtot);
    hipLaunchKernelGGL(k_chain, dim3(MAXLEN * (BATCH / CPB)), dim3(TPB), 0, stream,
                       zmean, zlv, W1, b1v, W2, b2v, segtot, outSeq, outErr);
  } else {
    hipLaunchKernelGGL(k_mono, dim3(MAXLEN * 8), dim3(64), 0, stream,
                       zmean, zlv, W1, b1v, W2, b2v, outSeq, outErr);
  }
}